// Round 1
// baseline (84.392 us; speedup 1.0000x reference)
//
#include <hip/hip_runtime.h>
#include <hip/hip_bf16.h>

// Problem constants (from reference)
#define BATCH    4096
#define IN_DIM   256
#define OUT_DIM  512
#define KDIM     512       // concat K: [silu(x) | spline(x)]
#define NKNOTS   64
#define NBASIS   60        // NUM_KNOTS - DEGREE - 1

typedef __attribute__((ext_vector_type(8))) short bf16x8;   // 8 bf16 in 4 VGPRs
typedef __attribute__((ext_vector_type(4))) float f32x4;

__device__ __forceinline__ short f2bf(float f) {
    __hip_bfloat16 h = __float2bfloat16(f);
    return *reinterpret_cast<short*>(&h);
}

// ---------------------------------------------------------------------------
// Kernel 1: A[b, 0:256] = silu(x[b,:]), A[b, 256:512] = spline(x[b,:])  (bf16)
// Uniform cubic B-spline: only 4 nonzero basis funcs; closed-form weights.
// ---------------------------------------------------------------------------
__global__ __launch_bounds__(256) void prep_a_kernel(
        const float* __restrict__ x, const float* __restrict__ cps,
        const float* __restrict__ knots, short* __restrict__ A) {
    int idx = blockIdx.x * 256 + threadIdx.x;      // b*IN_DIM + i
    int b = idx >> 8;          // / IN_DIM
    int i = idx & (IN_DIM - 1);

    float xv = x[idx];
    // silu
    float base = xv / (1.0f + __expf(-xv));

    // locate knot interval: knots = linspace(-1, 1, 64), h = 2/63
    float u = (xv + 1.0f) * 31.5f;                 // 31.5 = 1/h
    int   j = (int)floorf(u);
    float spline = 0.0f;
    if (j >= 0 && j <= 62) {
        float t  = (xv - knots[j]) * 31.5f;        // t in [0,1)
        float t2 = t * t, t3 = t2 * t;
        float omt = 1.0f - t;
        const float c6 = 1.0f / 6.0f;
        float w0 = omt * omt * omt * c6;                       // k = j-3
        float w1 = (3.0f*t3 - 6.0f*t2 + 4.0f) * c6;            // k = j-2
        float w2 = (-3.0f*t3 + 3.0f*t2 + 3.0f*t + 1.0f) * c6;  // k = j-1
        float w3 = t3 * c6;                                    // k = j
        const float* cp = cps + i * NKNOTS;
        int k0 = j - 3;
        // reference truncates basis to indices [0, NBASIS) — mask edges
        if (k0     >= 0 && k0     < NBASIS) spline += w0 * cp[k0];
        if (k0 + 1 >= 0 && k0 + 1 < NBASIS) spline += w1 * cp[k0 + 1];
        if (k0 + 2 >= 0 && k0 + 2 < NBASIS) spline += w2 * cp[k0 + 2];
        if (k0 + 3 >= 0 && k0 + 3 < NBASIS) spline += w3 * cp[k0 + 3];
    }

    A[b * KDIM + i]          = f2bf(base);
    A[b * KDIM + IN_DIM + i] = f2bf(spline);
}

// ---------------------------------------------------------------------------
// Kernel 2: Bt[n, k] = (k < 256 ? wb[k, n] : ws[k-256, n])   (bf16, K-contig)
// ---------------------------------------------------------------------------
__global__ __launch_bounds__(256) void prep_b_kernel(
        const float* __restrict__ wb, const float* __restrict__ ws,
        short* __restrict__ Bt) {
    int idx = blockIdx.x * 256 + threadIdx.x;      // n*KDIM + k
    int n = idx >> 9;          // / KDIM
    int k = idx & (KDIM - 1);
    float v = (k < IN_DIM) ? wb[k * OUT_DIM + n] : ws[(k - IN_DIM) * OUT_DIM + n];
    Bt[idx] = f2bf(v);
}

// ---------------------------------------------------------------------------
// Kernel 3: C[4096,512] = A @ Bt^T, bf16 MFMA 16x16x32, fp32 accum.
// 64x64 block tile, 4 waves of 32x32 each, BK=64, LDS stride 72 (2-way bank
// alias = free; rows stay 16B-aligned for b128 access).
// ---------------------------------------------------------------------------
#define BM 64
#define BN 64
#define BK 64
#define LDSS 72   // bf16 elems per LDS row (144 B, multiple of 16 B)

__global__ __launch_bounds__(256) void gemm_kernel(
        const short* __restrict__ A, const short* __restrict__ Bt,
        float* __restrict__ C) {
    __shared__ __align__(16) short As[BM * LDSS];
    __shared__ __align__(16) short Bs[BN * LDSS];

    const int m0 = blockIdx.y * BM;
    const int n0 = blockIdx.x * BN;
    const int tid  = threadIdx.x;
    const int lane = tid & 63;
    const int wave = tid >> 6;
    const int wm = (wave & 1) * 32;    // wave's 32x32 quadrant
    const int wn = (wave >> 1) * 32;
    const int fr   = lane & 15;        // fragment row/col index
    const int koff = (lane >> 4) * 8;  // k offset within the 32-wide MFMA K

    f32x4 acc[2][2] = {};

    // staging: 16 B chunks; tile = 64 rows x 8 chunks = 512 chunks; 2/thread
    const int c1 = tid, c2 = tid + 256;
    const int r1 = c1 >> 3, o1 = (c1 & 7) * 8;
    const int r2 = c2 >> 3, o2 = (c2 & 7) * 8;

    for (int k0 = 0; k0 < KDIM; k0 += BK) {
        *(uint4*)&As[r1 * LDSS + o1] = *(const uint4*)&A[(m0 + r1) * KDIM + k0 + o1];
        *(uint4*)&As[r2 * LDSS + o2] = *(const uint4*)&A[(m0 + r2) * KDIM + k0 + o2];
        *(uint4*)&Bs[r1 * LDSS + o1] = *(const uint4*)&Bt[(n0 + r1) * KDIM + k0 + o1];
        *(uint4*)&Bs[r2 * LDSS + o2] = *(const uint4*)&Bt[(n0 + r2) * KDIM + k0 + o2];
        __syncthreads();

        #pragma unroll
        for (int kk = 0; kk < BK; kk += 32) {
            bf16x8 a0 = *(const bf16x8*)&As[(wm + fr)      * LDSS + kk + koff];
            bf16x8 a1 = *(const bf16x8*)&As[(wm + 16 + fr) * LDSS + kk + koff];
            bf16x8 b0 = *(const bf16x8*)&Bs[(wn + fr)      * LDSS + kk + koff];
            bf16x8 b1 = *(const bf16x8*)&Bs[(wn + 16 + fr) * LDSS + kk + koff];
            acc[0][0] = __builtin_amdgcn_mfma_f32_16x16x32_bf16(a0, b0, acc[0][0], 0, 0, 0);
            acc[0][1] = __builtin_amdgcn_mfma_f32_16x16x32_bf16(a0, b1, acc[0][1], 0, 0, 0);
            acc[1][0] = __builtin_amdgcn_mfma_f32_16x16x32_bf16(a1, b0, acc[1][0], 0, 0, 0);
            acc[1][1] = __builtin_amdgcn_mfma_f32_16x16x32_bf16(a1, b1, acc[1][1], 0, 0, 0);
        }
        __syncthreads();
    }

    // epilogue: C/D layout col = lane&15, row = (lane>>4)*4 + reg  [m89-verified]
    const int rbase = (lane >> 4) * 4;
    #pragma unroll
    for (int mt = 0; mt < 2; ++mt) {
        #pragma unroll
        for (int nt = 0; nt < 2; ++nt) {
            #pragma unroll
            for (int r = 0; r < 4; ++r) {
                int row = m0 + wm + mt * 16 + rbase + r;
                int col = n0 + wn + nt * 16 + fr;
                C[row * OUT_DIM + col] = acc[mt][nt][r];
            }
        }
    }
}

// ---------------------------------------------------------------------------
extern "C" void kernel_launch(void* const* d_in, const int* in_sizes, int n_in,
                              void* d_out, int out_size, void* d_ws, size_t ws_size,
                              hipStream_t stream) {
    const float* x     = (const float*)d_in[0];
    const float* wb    = (const float*)d_in[1];
    const float* ws    = (const float*)d_in[2];
    const float* cps   = (const float*)d_in[3];
    const float* knots = (const float*)d_in[4];
    float* out = (float*)d_out;

    short* Abf = (short*)d_ws;                                   // 4096*512*2 = 4 MB
    short* Btb = (short*)((char*)d_ws + (size_t)BATCH * KDIM * 2); // 512*512*2 = 0.5 MB

    prep_a_kernel<<<BATCH * IN_DIM / 256, 256, 0, stream>>>(x, cps, knots, Abf);
    prep_b_kernel<<<OUT_DIM * KDIM / 256, 256, 0, stream>>>(wb, ws, Btb);

    dim3 grid(OUT_DIM / BN, BATCH / BM);
    gemm_kernel<<<grid, 256, 0, stream>>>(Abf, Btb, out);
}